// Round 7
// baseline (904.347 us; speedup 1.0000x reference)
//
#include <hip/hip_runtime.h>

#define N_NODES 10000
#define N_EDGES 160000
#define CIN 64
#define COUT 128
#define KTOT 125
#define NBINS (N_NODES * KTOT)          // 1,250,000
#define NPAIRS (N_EDGES * 8)            // 1,280,000
#define EPS 1e-5f

#define CDIV(a,b) (((a)+(b)-1)/(b))

typedef __attribute__((ext_vector_type(8))) short short8;
typedef __attribute__((ext_vector_type(4))) float floatx4;

static __device__ __forceinline__ unsigned short f2b(float f) {
  union { float f; unsigned u; } v; v.f = f;
  unsigned r = v.u + 0x7FFFu + ((v.u >> 16) & 1u);
  return (unsigned short)(r >> 16);
}
static __device__ __forceinline__ float b2f(unsigned short u) {
  union { unsigned u; float f; } v; v.u = ((unsigned)u) << 16;
  return v.f;
}

typedef __attribute__((address_space(1))) const unsigned int guint;
typedef __attribute__((address_space(3))) unsigned int luint;
static __device__ __forceinline__ void ld_g2l16(const void* g, void* l) {
  __builtin_amdgcn_global_load_lds((guint*)g, (luint*)l, 16, 0, 0);
}

// ---------------- (dst,k)-pair counting sort ----------------
static __device__ __forceinline__ void spline_corners(const float* __restrict__ attr, int e,
                                                      float* w8, int* k8) {
  float v0 = attr[e * 3 + 0] * 4.f;
  float v1 = attr[e * 3 + 1] * 4.f;
  float v2 = attr[e * 3 + 2] * 4.f;
  float b0 = floorf(v0), b1 = floorf(v1), b2 = floorf(v2);
  float f0 = v0 - b0, f1 = v1 - b1, f2 = v2 - b2;
  int i0 = (int)b0, i1 = (int)b1, i2 = (int)b2;
#pragma unroll
  for (int combo = 0; combo < 8; combo++) {
    int bit0 = combo & 1, bit1 = (combo >> 1) & 1, bit2 = (combo >> 2) & 1;
    w8[combo] = (bit0 ? f0 : 1.f - f0) * (bit1 ? f1 : 1.f - f1) * (bit2 ? f2 : 1.f - f2);
    int k0 = min(max(i0 + bit0, 0), 4);
    int k1 = min(max(i1 + bit1, 0), 4);
    int k2 = min(max(i2 + bit2, 0), 4);
    k8[combo] = k0 * 25 + k1 * 5 + k2;
  }
}

__global__ void pair_count(const int* __restrict__ dst, const float* __restrict__ attr,
                           int* __restrict__ cnt2, int E) {
  int e = blockIdx.x * 256 + threadIdx.x;
  if (e >= E) return;
  int d = dst[e];
  float w8[8]; int k8[8];
  spline_corners(attr, e, w8, k8);
#pragma unroll
  for (int c = 0; c < 8; c++) atomicAdd(&cnt2[d * KTOT + k8[c]], 1);
}

// cur2 pre-seeded with rowptr2 values by scan_c -> atomicAdd gives absolute slot.
// Pair record: int2 {src, float-bits(w)} -- single 8B store (halves cacheline traffic).
__global__ void pair_fill(const int* __restrict__ src, const int* __restrict__ dst,
                          const float* __restrict__ attr, int* __restrict__ cur2,
                          int2* __restrict__ pairs, int E) {
  int e = blockIdx.x * 256 + threadIdx.x;
  if (e >= E) return;
  int s = src[e], d = dst[e];
  float w8[8]; int k8[8];
  spline_corners(attr, e, w8, k8);
#pragma unroll
  for (int c = 0; c < 8; c++) {
    int b = d * KTOT + k8[c];
    int pos = atomicAdd(&cur2[b], 1);
    int2 rec; rec.x = s; rec.y = __float_as_int(w8[c]);
    pairs[pos] = rec;
  }
}

// ---------------- 3-kernel exclusive scan over NBINS ints ----------------
__global__ void scan_a(const int* __restrict__ in, int* __restrict__ bsum, int n) {
  __shared__ int red[256];
  int base = blockIdx.x * 2048 + threadIdx.x * 8;
  int s = 0;
#pragma unroll
  for (int j = 0; j < 8; j++) { int i = base + j; if (i < n) s += in[i]; }
  red[threadIdx.x] = s;
  __syncthreads();
  for (int st = 128; st > 0; st >>= 1) {
    if (threadIdx.x < st) red[threadIdx.x] += red[threadIdx.x + st];
    __syncthreads();
  }
  if (threadIdx.x == 0) bsum[blockIdx.x] = red[0];
}

// also zeroes the stats block (piggyback; must run before any finalize kernel)
__global__ void scan_b(const int* __restrict__ bsum, int* __restrict__ boff, int nb,
                       int* __restrict__ rowptr2, int nbins, float* __restrict__ stats) {
  for (int i = threadIdx.x; i < 6 * 128; i += 256) stats[i] = 0.f;
  __shared__ int buf[256];
  __shared__ int carry;
  if (threadIdx.x == 0) carry = 0;
  __syncthreads();
  for (int base = 0; base < nb; base += 256) {
    int i = base + threadIdx.x;
    int v = (i < nb) ? bsum[i] : 0;
    buf[threadIdx.x] = v;
    __syncthreads();
    for (int s = 1; s < 256; s <<= 1) {
      int t = (threadIdx.x >= s) ? buf[threadIdx.x - s] : 0;
      __syncthreads();
      buf[threadIdx.x] += t;
      __syncthreads();
    }
    if (i < nb) boff[i] = carry + buf[threadIdx.x] - v;
    __syncthreads();
    if (threadIdx.x == 255) carry += buf[255];
    __syncthreads();
  }
  if (threadIdx.x == 0) rowptr2[nbins] = carry;
}

// writes rowptr2[i] and seeds cur2[i] with the same value
__global__ void scan_c(const int* __restrict__ in, const int* __restrict__ boff,
                       int* __restrict__ rowptr2, int* __restrict__ cur2, int n) {
  __shared__ int buf[256];
  int base = blockIdx.x * 2048 + threadIdx.x * 8;
  int v[8], p[8];
  int s = 0;
#pragma unroll
  for (int j = 0; j < 8; j++) {
    int i = base + j;
    v[j] = (i < n) ? in[i] : 0;
    p[j] = s;
    s += v[j];
  }
  buf[threadIdx.x] = s;
  __syncthreads();
  for (int st = 1; st < 256; st <<= 1) {
    int t = (threadIdx.x >= st) ? buf[threadIdx.x - st] : 0;
    __syncthreads();
    buf[threadIdx.x] += t;
    __syncthreads();
  }
  int thr_excl = buf[threadIdx.x] - s;
  int b0 = boff[blockIdx.x];
#pragma unroll
  for (int j = 0; j < 8; j++) {
    int i = base + j;
    if (i < n) { int val = b0 + thr_excl + p[j]; rowptr2[i] = val; cur2[i] = val; }
  }
}

// ---------------- one-shot convert: xb + all weight transposes ----------------
__global__ void convert_all(const float* __restrict__ x, const float* __restrict__ W1,
                            const float* __restrict__ W2, const float* __restrict__ Wr1,
                            const float* __restrict__ Wrsc, const float* __restrict__ Wr2,
                            const float* __restrict__ Wsc,
                            unsigned short* __restrict__ xb, unsigned short* __restrict__ W1aug,
                            unsigned short* __restrict__ W2t, unsigned short* __restrict__ rootBt,
                            unsigned short* __restrict__ Wr2t) {
  long i = (long)blockIdx.x * 256 + threadIdx.x;
  const long n0 = 640000, n1 = n0 + 1024000, n2 = n1 + 2048000,
             n3 = n2 + 8192, n4 = n3 + 8192, n5 = n4 + 16384, n6 = n5 + 1024000;
  if (i < n0) {
    xb[i] = f2b(x[i]);
  } else if (i < n1) {
    long j = i - n0; int k = (int)(j >> 7), c = (int)(j & 127);
    W1aug[(long)c * 8000 + k] = f2b(W1[j]);
  } else if (i < n2) {
    long j = i - n1; int k = (int)(j >> 7), c = (int)(j & 127);
    W2t[(long)c * 16000 + k] = f2b(W2[j]);
  } else if (i < n3) {
    long j = i - n2; int k = (int)(j >> 7), c = (int)(j & 127);
    rootBt[c * 64 + k] = f2b(Wr1[j]);
  } else if (i < n4) {
    long j = i - n3; int k = (int)(j >> 7), c = (int)(j & 127);
    rootBt[(128 + c) * 64 + k] = f2b(Wrsc[j]);
  } else if (i < n5) {
    long j = i - n4; int k = (int)(j >> 7), c = (int)(j & 127);
    Wr2t[c * 128 + k] = f2b(Wr2[j]);
  } else if (i < n6) {
    long j = i - n5;
    int c = (int)(j / 8000), kk = (int)(j % 8000);
    W1aug[(long)(128 + c) * 8000 + kk] = f2b(Wsc[(kk & 63) * 128 + c]);
  }
}

// ---------------- scatter: one wave per 8 consecutive bins, register accumulate --
template<int C>
__global__ __launch_bounds__(256) void scatter_bins(
    const unsigned short* __restrict__ Xb, const int* __restrict__ rowptr2,
    const int2* __restrict__ pairs,
    unsigned short* __restrict__ accb, int bin0, int nbins_chunk) {
  int wb0 = (blockIdx.x * 4 + (threadIdx.x >> 6)) * 8;
  if (wb0 >= nbins_chunk) return;
  int lane = threadIdx.x & 63;
  int bin = bin0 + wb0;
  int bounds = 0;
  if (lane < 9) bounds = rowptr2[bin + lane];
  int b[9];
#pragma unroll
  for (int j = 0; j < 9; j++) b[j] = __shfl(bounds, j, 64);
#pragma unroll
  for (int j = 0; j < 8; j++) {
    int wb = wb0 + j;
    if (wb >= nbins_chunk) break;
    float a0 = 0.f, a1 = 0.f;
    for (int p = b[j]; p < b[j + 1]; p++) {
      int2 rec = pairs[p];
      float w = __int_as_float(rec.y);
      if (C == 64) {
        a0 += w * b2f(Xb[(long)rec.x * 64 + lane]);
      } else {
        unsigned u = *(const unsigned*)(Xb + (long)rec.x * 128 + lane * 2);
        a0 += w * b2f((unsigned short)(u & 0xffffu));
        a1 += w * b2f((unsigned short)(u >> 16));
      }
    }
    if (C == 64) {
      accb[(long)wb * 64 + lane] = f2b(a0);
    } else {
      unsigned pk = (unsigned)f2b(a0) | ((unsigned)f2b(a1) << 16);
      *(unsigned*)(accb + (long)wb * 128 + lane * 2) = pk;
    }
  }
}

// ---------------- LDS-staged MFMA GEMM, 128 output cols ----------------
template<int NCOLS, bool ATOMIC>
__global__ __launch_bounds__(256, 2) void gemm_tile(const unsigned short* __restrict__ A,
                                                    const unsigned short* __restrict__ Bt,
                                                    float* __restrict__ C, int M, int K) {
  __shared__ unsigned short As[128 * 32];
  __shared__ unsigned short Bs[128 * 32];
  int wid = threadIdx.x >> 6, lane = threadIdx.x & 63;
  int row0 = blockIdx.x * 128;
  int nslice = gridDim.y;
  int kslice = CDIV(K / 32, nslice) * 32;
  int kbeg = blockIdx.y * kslice;
  int kend = kbeg + kslice; if (kend > K) kend = K;
  if (kbeg >= K) return;

  int sub = lane & 3;
  int rload = lane >> 2;
  int q = lane >> 4, m16 = lane & 15;

  floatx4 acc[2][8];
#pragma unroll
  for (int t = 0; t < 2; t++)
#pragma unroll
    for (int c = 0; c < 8; c++) acc[t][c] = (floatx4){0.f, 0.f, 0.f, 0.f};

  for (int k0 = kbeg; k0 < kend; k0 += 32) {
    __syncthreads();
#pragma unroll
    for (int j = 0; j < 2; j++) {
      int tr = (wid * 2 + j) * 16 + rload;
      int gr = row0 + tr; if (gr >= M) gr = M - 1;
      ld_g2l16(A + (long)gr * K + k0 + sub * 8, As + (wid * 2 + j) * 512);
      ld_g2l16(Bt + (long)tr * K + k0 + sub * 8, Bs + (wid * 2 + j) * 512);
    }
    __syncthreads();
#pragma unroll
    for (int t = 0; t < 2; t++) {
      int arow = wid * 32 + t * 16 + m16;
      short8 a = *(const short8*)(As + arow * 32 + q * 8);
#pragma unroll
      for (int c = 0; c < 8; c++) {
        short8 b = *(const short8*)(Bs + (c * 16 + m16) * 32 + q * 8);
        acc[t][c] = __builtin_amdgcn_mfma_f32_16x16x32_bf16(a, b, acc[t][c], 0, 0, 0);
      }
    }
  }

#pragma unroll
  for (int t = 0; t < 2; t++) {
#pragma unroll
    for (int c = 0; c < 8; c++) {
#pragma unroll
      for (int r = 0; r < 4; r++) {
        int orow = row0 + wid * 32 + t * 16 + q * 4 + r;
        if (orow < M) {
          float* p = &C[(long)orow * NCOLS + c * 16 + m16];
          if (ATOMIC) atomicAdd(p, acc[t][c][r]);
          else *p = acc[t][c][r];
        }
      }
    }
  }
}

// ---------------- 128x256 tile GEMM (conv1+shortcut in one A pass) ----------------
template<bool ATOMIC>
__global__ __launch_bounds__(256, 2) void gemm_tile_w256(const unsigned short* __restrict__ A,
                                                         const unsigned short* __restrict__ Bt,
                                                         float* __restrict__ C, int M, int K) {
  __shared__ unsigned short As[128 * 32];
  __shared__ unsigned short Bs[256 * 32];
  int wid = threadIdx.x >> 6, lane = threadIdx.x & 63;
  int row0 = blockIdx.x * 128;
  int nslice = gridDim.y;
  int kslice = CDIV(K / 32, nslice) * 32;
  int kbeg = blockIdx.y * kslice;
  int kend = kbeg + kslice; if (kend > K) kend = K;
  if (kbeg >= K) return;

  int sub = lane & 3;
  int rload = lane >> 2;
  int q = lane >> 4, m16 = lane & 15;

  floatx4 acc[2][16];
#pragma unroll
  for (int t = 0; t < 2; t++)
#pragma unroll
    for (int c = 0; c < 16; c++) acc[t][c] = (floatx4){0.f, 0.f, 0.f, 0.f};

  for (int k0 = kbeg; k0 < kend; k0 += 32) {
    __syncthreads();
#pragma unroll
    for (int j = 0; j < 2; j++) {
      int tr = (wid * 2 + j) * 16 + rload;
      int gr = row0 + tr; if (gr >= M) gr = M - 1;
      ld_g2l16(A + (long)gr * K + k0 + sub * 8, As + (wid * 2 + j) * 512);
    }
#pragma unroll
    for (int j = 0; j < 4; j++) {
      int tr = (wid * 4 + j) * 16 + rload;
      ld_g2l16(Bt + (long)tr * K + k0 + sub * 8, Bs + (wid * 4 + j) * 512);
    }
    __syncthreads();
#pragma unroll
    for (int t = 0; t < 2; t++) {
      int arow = wid * 32 + t * 16 + m16;
      short8 a = *(const short8*)(As + arow * 32 + q * 8);
#pragma unroll
      for (int c = 0; c < 16; c++) {
        short8 b = *(const short8*)(Bs + (c * 16 + m16) * 32 + q * 8);
        acc[t][c] = __builtin_amdgcn_mfma_f32_16x16x32_bf16(a, b, acc[t][c], 0, 0, 0);
      }
    }
  }

#pragma unroll
  for (int t = 0; t < 2; t++) {
#pragma unroll
    for (int c = 0; c < 16; c++) {
#pragma unroll
      for (int r = 0; r < 4; r++) {
        int orow = row0 + wid * 32 + t * 16 + q * 4 + r;
        if (orow < M) {
          float* p = &C[(long)orow * 256 + c * 16 + m16];
          if (ATOMIC) atomicAdd(p, acc[t][c][r]);
          else *p = acc[t][c][r];
        }
      }
    }
  }
}

// ---------------- epilogues ----------------
static __device__ __forceinline__ float node_deg(const int* __restrict__ rowptr2, int r) {
  return (float)((rowptr2[(r + 1) * KTOT] - rowptr2[r * KTOT]) >> 3);
}

__global__ void finalize_stats(const float* __restrict__ msgaug, const float* __restrict__ root,
                               const float* __restrict__ bias,
                               const int* __restrict__ rowptr2,
                               float* __restrict__ out, float* __restrict__ stats, int n) {
  int c = threadIdx.x & 127;
  float bv = bias[c];
  float s = 0.f, s2 = 0.f;
  long tot = (long)n * COUT;
  long stride = (long)gridDim.x * 256;
  for (long i = (long)blockIdx.x * 256 + threadIdx.x; i < tot; i += stride) {
    int r = (int)(i >> 7);
    float v = msgaug[(long)r * 256 + c] / fmaxf(node_deg(rowptr2, r), 1.0f)
            + root[(long)r * 256 + c] + bv;
    out[i] = v;
    s += v; s2 += v * v;
  }
  __shared__ float ls[256], ls2[256];
  ls[threadIdx.x] = s; ls2[threadIdx.x] = s2;
  __syncthreads();
  if (threadIdx.x < 128) {
    atomicAdd(&stats[c], ls[threadIdx.x] + ls[threadIdx.x + 128]);
    atomicAdd(&stats[128 + c], ls2[threadIdx.x] + ls2[threadIdx.x + 128]);
  }
}

__global__ void finalize2_dual(const float* __restrict__ msg2, const float* __restrict__ rootb2,
                               const float* __restrict__ b2, const float* __restrict__ msgaug,
                               const float* __restrict__ rootb, const float* __restrict__ bsc,
                               const int* __restrict__ rowptr2, float* __restrict__ h2r,
                               float* __restrict__ sraw, float* __restrict__ stats2,
                               float* __restrict__ statssc, int n) {
  int c = threadIdx.x & 127;
  float bv2 = b2[c], bvsc = bsc[c];
  float sa = 0.f, sb = 0.f, ta = 0.f, tb = 0.f;
  long tot = (long)n * COUT;
  long stride = (long)gridDim.x * 256;
  for (long i = (long)blockIdx.x * 256 + threadIdx.x; i < tot; i += stride) {
    int r = (int)(i >> 7);
    float invdeg = 1.0f / fmaxf(node_deg(rowptr2, r), 1.0f);
    float v2 = msg2[i] * invdeg + rootb2[i] + bv2;
    h2r[i] = v2;
    sa += v2; sb += v2 * v2;
    float vs = msgaug[(long)r * 256 + 128 + c] * invdeg
             + rootb[(long)r * 256 + 128 + c] + bvsc;
    sraw[i] = vs;
    ta += vs; tb += vs * vs;
  }
  __shared__ float l0[256], l1[256], l2[256], l3[256];
  l0[threadIdx.x] = sa; l1[threadIdx.x] = sb; l2[threadIdx.x] = ta; l3[threadIdx.x] = tb;
  __syncthreads();
  if (threadIdx.x < 128) {
    atomicAdd(&stats2[c], l0[threadIdx.x] + l0[threadIdx.x + 128]);
    atomicAdd(&stats2[128 + c], l1[threadIdx.x] + l1[threadIdx.x + 128]);
    atomicAdd(&statssc[c], l2[threadIdx.x] + l2[threadIdx.x + 128]);
    atomicAdd(&statssc[128 + c], l3[threadIdx.x] + l3[threadIdx.x + 128]);
  }
}

__global__ void bn_elu_kernel(float* __restrict__ h, unsigned short* __restrict__ hb,
                              const float* __restrict__ stats, const float* __restrict__ g,
                              const float* __restrict__ be, int n) {
  long i = (long)blockIdx.x * 256 + threadIdx.x;
  if (i >= (long)n * COUT) return;
  int c = (int)(i & 127);
  float inv_n = 1.0f / n;
  float mu = stats[c] * inv_n;
  float var = stats[128 + c] * inv_n - mu * mu;
  float v = (h[i] - mu) * rsqrtf(var + EPS) * g[c] + be[c];
  v = v > 0.f ? v : expm1f(v);
  h[i] = v;
  hb[i] = f2b(v);
}

__global__ void final_out_kernel(const float* __restrict__ h2, const float* __restrict__ sraw,
                                 const float* __restrict__ st2, const float* __restrict__ stsc,
                                 const float* __restrict__ g2, const float* __restrict__ be2,
                                 const float* __restrict__ gsc, const float* __restrict__ besc,
                                 float* __restrict__ out, int n) {
  long i = (long)blockIdx.x * 256 + threadIdx.x;
  if (i >= (long)n * COUT) return;
  int c = (int)(i & 127);
  float inv_n = 1.0f / n;
  float mu2 = st2[c] * inv_n;
  float var2 = st2[128 + c] * inv_n - mu2 * mu2;
  float a = (h2[i] - mu2) * rsqrtf(var2 + EPS) * g2[c] + be2[c];
  float musc = stsc[c] * inv_n;
  float varsc = stsc[128 + c] * inv_n - musc * musc;
  float b = (sraw[i] - musc) * rsqrtf(varsc + EPS) * gsc[c] + besc[c];
  float v = a + b;
  out[i] = v > 0.f ? v : expm1f(v);
}

// ---------------- host ----------------
extern "C" void kernel_launch(void* const* d_in, const int* in_sizes, int n_in,
                              void* d_out, int out_size, void* d_ws, size_t ws_size,
                              hipStream_t stream) {
  const float* x    = (const float*)d_in[0];
  const int*   eidx = (const int*)d_in[1];
  const float* attr = (const float*)d_in[2];
  const float* W1   = (const float*)d_in[3];
  const float* Wr1  = (const float*)d_in[4];
  const float* b1   = (const float*)d_in[5];
  const float* g1   = (const float*)d_in[6];
  const float* be1  = (const float*)d_in[7];
  const float* W2   = (const float*)d_in[8];
  const float* Wr2  = (const float*)d_in[9];
  const float* b2   = (const float*)d_in[10];
  const float* g2   = (const float*)d_in[11];
  const float* be2  = (const float*)d_in[12];
  const float* Wsc  = (const float*)d_in[13];
  const float* Wrsc = (const float*)d_in[14];
  const float* bsc  = (const float*)d_in[15];
  const float* gsc  = (const float*)d_in[16];
  const float* besc = (const float*)d_in[17];
  float* out = (float*)d_out;

  const int* src = eidx;
  const int* dst = eidx + N_EDGES;

  char* base = (char*)d_ws;
  size_t off = 0;
  auto alloc = [&](size_t bytes) -> char* {
    char* p = base + off;
    off += (bytes + 255) & ~(size_t)255;
    return p;
  };
  int* cnt2   = (int*)alloc((size_t)NBINS * 4);
  int* cur2   = (int*)alloc((size_t)NBINS * 4);
  int* rowptr2= (int*)alloc((size_t)(NBINS + 1) * 4);
  const int NB_SCAN = CDIV(NBINS, 2048);
  int* bsum   = (int*)alloc((size_t)(NB_SCAN + 1) * 4);
  int* boff   = (int*)alloc((size_t)(NB_SCAN + 1) * 4);
  int2* pairs = (int2*)alloc((size_t)NPAIRS * 8);
  unsigned short* xb    = (unsigned short*)alloc((size_t)N_NODES * CIN * 2);
  unsigned short* hb    = (unsigned short*)alloc((size_t)N_NODES * COUT * 2);
  unsigned short* W1aug = (unsigned short*)alloc((size_t)256 * KTOT * CIN * 2);
  unsigned short* W2t   = (unsigned short*)alloc((size_t)COUT * KTOT * COUT * 2);
  unsigned short* rootBt= (unsigned short*)alloc((size_t)256 * CIN * 2);
  unsigned short* Wr2t  = (unsigned short*)alloc((size_t)COUT * COUT * 2);
  float* msgaug= (float*)alloc((size_t)N_NODES * 256 * 4);    // conv1+shortcut (zeroed)
  float* msg2  = (float*)alloc((size_t)N_NODES * COUT * 4);   // conv2 (zeroed, adjacent)
  float* rootb = (float*)alloc((size_t)N_NODES * 256 * 4);    // [Wr1 | Wrsc] outputs
  float* rootb2= (float*)alloc((size_t)N_NODES * COUT * 4);
  float* h1    = (float*)alloc((size_t)N_NODES * COUT * 4);
  float* h2r   = (float*)alloc((size_t)N_NODES * COUT * 4);
  float* sraw  = (float*)alloc((size_t)N_NODES * COUT * 4);
  float* stats = (float*)alloc(6 * 128 * 4);
  unsigned short* accb = (unsigned short*)(base + off);
  size_t avail = (ws_size > off) ? (ws_size - off) : 0;
  size_t per_node = (size_t)KTOT * COUT * 2;
  size_t chmax = avail / per_node;
  int CH = (int)((chmax < (size_t)N_NODES) ? chmax : (size_t)N_NODES);
  if (CH < 1) CH = 1;
  const int SPLIT = 10;

  hipMemsetAsync(cnt2, 0, (size_t)NBINS * 4, stream);
  hipMemsetAsync(msgaug, 0, (size_t)N_NODES * (256 + 128) * 4, stream); // msgaug + msg2

  // (dst,k)-pair counting sort (stats zeroed in scan_b, cur2 seeded in scan_c)
  pair_count<<<CDIV(N_EDGES, 256), 256, 0, stream>>>(dst, attr, cnt2, N_EDGES);
  scan_a<<<NB_SCAN, 256, 0, stream>>>(cnt2, bsum, NBINS);
  scan_b<<<1, 256, 0, stream>>>(bsum, boff, NB_SCAN, rowptr2, NBINS, stats);
  scan_c<<<NB_SCAN, 256, 0, stream>>>(cnt2, boff, rowptr2, cur2, NBINS);
  pair_fill<<<CDIV(N_EDGES, 256), 256, 0, stream>>>(src, dst, attr, cur2, pairs, N_EDGES);

  const long CONV_TOT = 640000L + 1024000L + 2048000L + 8192 + 8192 + 16384 + 1024000L;
  convert_all<<<CDIV(CONV_TOT, 256), 256, 0, stream>>>(x, W1, W2, Wr1, Wrsc, Wr2, Wsc,
                                                       xb, W1aug, W2t, rootBt, Wr2t);

  // ---- conv1 (+ shortcut spline via augmented cols 128..255, single A pass) ----
  for (int c0 = 0; c0 < N_NODES; c0 += CH) {
    int cm = (N_NODES - c0 < CH) ? (N_NODES - c0) : CH;
    int nbc = cm * KTOT;
    scatter_bins<64><<<CDIV(nbc, 32), 256, 0, stream>>>(xb, rowptr2, pairs, accb,
                                                        c0 * KTOT, nbc);
    dim3 g(CDIV(cm, 128), SPLIT);
    gemm_tile_w256<true><<<g, 256, 0, stream>>>(accb, W1aug, msgaug + (size_t)c0 * 256,
                                                cm, KTOT * CIN);
  }
  gemm_tile_w256<false><<<dim3(CDIV(N_NODES, 128), 1), 256, 0, stream>>>(
      xb, rootBt, rootb, N_NODES, CIN);
  finalize_stats<<<64, 256, 0, stream>>>(msgaug, rootb, b1, rowptr2, h1, stats, N_NODES);
  bn_elu_kernel<<<CDIV(N_NODES * COUT, 256), 256, 0, stream>>>(h1, hb, stats, g1, be1, N_NODES);

  // ---- conv2 ----
  for (int c0 = 0; c0 < N_NODES; c0 += CH) {
    int cm = (N_NODES - c0 < CH) ? (N_NODES - c0) : CH;
    int nbc = cm * KTOT;
    scatter_bins<128><<<CDIV(nbc, 32), 256, 0, stream>>>(hb, rowptr2, pairs, accb,
                                                         c0 * KTOT, nbc);
    dim3 g(CDIV(cm, 128), SPLIT);
    gemm_tile<COUT, true><<<g, 256, 0, stream>>>(accb, W2t, msg2 + (size_t)c0 * COUT,
                                                 cm, KTOT * COUT);
  }
  gemm_tile<COUT, false><<<dim3(CDIV(N_NODES, 128), 1), 256, 0, stream>>>(
      hb, Wr2t, rootb2, N_NODES, COUT);
  finalize2_dual<<<64, 256, 0, stream>>>(msg2, rootb2, b2, msgaug, rootb, bsc, rowptr2,
                                         h2r, sraw, stats + 256, stats + 512, N_NODES);

  // ---- output ----
  final_out_kernel<<<CDIV(N_NODES * COUT, 256), 256, 0, stream>>>(
      h2r, sraw, stats + 256, stats + 512, g2, be2, gsc, besc, out, N_NODES);
}

// Round 8
// 891.993 us; speedup vs baseline: 1.0138x; 1.0138x over previous
//
#include <hip/hip_runtime.h>

#define N_NODES 10000
#define N_EDGES 160000
#define CIN 64
#define COUT 128
#define KTOT 125
#define NBINS (N_NODES * KTOT)          // 1,250,000
#define NPAIRS (N_EDGES * 8)            // 1,280,000
#define EPS 1e-5f

#define CDIV(a,b) (((a)+(b)-1)/(b))

typedef __attribute__((ext_vector_type(8))) short short8;
typedef __attribute__((ext_vector_type(4))) float floatx4;

static __device__ __forceinline__ unsigned short f2b(float f) {
  union { float f; unsigned u; } v; v.f = f;
  unsigned r = v.u + 0x7FFFu + ((v.u >> 16) & 1u);
  return (unsigned short)(r >> 16);
}
static __device__ __forceinline__ float b2f(unsigned short u) {
  union { unsigned u; float f; } v; v.u = ((unsigned)u) << 16;
  return v.f;
}

typedef __attribute__((address_space(1))) const unsigned int guint;
typedef __attribute__((address_space(3))) unsigned int luint;
static __device__ __forceinline__ void ld_g2l16(const void* g, void* l) {
  __builtin_amdgcn_global_load_lds((guint*)g, (luint*)l, 16, 0, 0);
}

// ---------------- edge CSR (dst-sorted edge order for write locality) ----------
__global__ void ecount(const int* __restrict__ dst, int* __restrict__ ecnt, int E) {
  int e = blockIdx.x * 256 + threadIdx.x;
  if (e < E) atomicAdd(&ecnt[dst[e]], 1);
}

// single-block exclusive scan over n=10000; also seeds ecur with the prefix
__global__ void escan(const int* __restrict__ cnt, int* __restrict__ rowptr,
                      int* __restrict__ cur, int n) {
  __shared__ int buf[256];
  __shared__ int carry;
  if (threadIdx.x == 0) { carry = 0; rowptr[0] = 0; }
  __syncthreads();
  for (int base = 0; base < n; base += 256) {
    int i = base + threadIdx.x;
    int v = (i < n) ? cnt[i] : 0;
    buf[threadIdx.x] = v;
    __syncthreads();
    for (int s = 1; s < 256; s <<= 1) {
      int t = (threadIdx.x >= s) ? buf[threadIdx.x - s] : 0;
      __syncthreads();
      buf[threadIdx.x] += t;
      __syncthreads();
    }
    if (i < n) {
      int incl = carry + buf[threadIdx.x];
      rowptr[i + 1] = incl;
      cur[i] = incl - v;
    }
    __syncthreads();
    if (threadIdx.x == 255) carry += buf[255];
    __syncthreads();
  }
}

__global__ void efill(const int* __restrict__ dst, int* __restrict__ ecur,
                      int* __restrict__ eorder, int E) {
  int e = blockIdx.x * 256 + threadIdx.x;
  if (e >= E) return;
  int pos = atomicAdd(&ecur[dst[e]], 1);
  eorder[pos] = e;
}

// ---------------- (dst,k)-pair counting sort ----------------
static __device__ __forceinline__ void spline_corners(const float* __restrict__ attr, int e,
                                                      float* w8, int* k8) {
  float v0 = attr[e * 3 + 0] * 4.f;
  float v1 = attr[e * 3 + 1] * 4.f;
  float v2 = attr[e * 3 + 2] * 4.f;
  float b0 = floorf(v0), b1 = floorf(v1), b2 = floorf(v2);
  float f0 = v0 - b0, f1 = v1 - b1, f2 = v2 - b2;
  int i0 = (int)b0, i1 = (int)b1, i2 = (int)b2;
#pragma unroll
  for (int combo = 0; combo < 8; combo++) {
    int bit0 = combo & 1, bit1 = (combo >> 1) & 1, bit2 = (combo >> 2) & 1;
    w8[combo] = (bit0 ? f0 : 1.f - f0) * (bit1 ? f1 : 1.f - f1) * (bit2 ? f2 : 1.f - f2);
    int k0 = min(max(i0 + bit0, 0), 4);
    int k1 = min(max(i1 + bit1, 0), 4);
    int k2 = min(max(i2 + bit2, 0), 4);
    k8[combo] = k0 * 25 + k1 * 5 + k2;
  }
}

// iterate edges in dst-sorted order -> cnt2 atomics localized
__global__ void pair_count(const int* __restrict__ eorder, const int* __restrict__ dst,
                           const float* __restrict__ attr, int* __restrict__ cnt2, int E) {
  int i = blockIdx.x * 256 + threadIdx.x;
  if (i >= E) return;
  int e = eorder[i];
  int d = dst[e];
  float w8[8]; int k8[8];
  spline_corners(attr, e, w8, k8);
#pragma unroll
  for (int c = 0; c < 8; c++) atomicAdd(&cnt2[d * KTOT + k8[c]], 1);
}

// cur2 pre-seeded with rowptr2 by scan_c; dst-sorted order -> stores land in the
// node's compact ~1KB slot window (coalesced lines instead of 1 line per pair).
__global__ void pair_fill(const int* __restrict__ eorder, const int* __restrict__ src,
                          const int* __restrict__ dst, const float* __restrict__ attr,
                          int* __restrict__ cur2, int2* __restrict__ pairs, int E) {
  int i = blockIdx.x * 256 + threadIdx.x;
  if (i >= E) return;
  int e = eorder[i];
  int s = src[e], d = dst[e];
  float w8[8]; int k8[8];
  spline_corners(attr, e, w8, k8);
#pragma unroll
  for (int c = 0; c < 8; c++) {
    int b = d * KTOT + k8[c];
    int pos = atomicAdd(&cur2[b], 1);
    int2 rec; rec.x = s; rec.y = __float_as_int(w8[c]);
    pairs[pos] = rec;
  }
}

// ---------------- 3-kernel exclusive scan over NBINS ints ----------------
__global__ void scan_a(const int* __restrict__ in, int* __restrict__ bsum, int n) {
  __shared__ int red[256];
  int base = blockIdx.x * 2048 + threadIdx.x * 8;
  int s = 0;
#pragma unroll
  for (int j = 0; j < 8; j++) { int i = base + j; if (i < n) s += in[i]; }
  red[threadIdx.x] = s;
  __syncthreads();
  for (int st = 128; st > 0; st >>= 1) {
    if (threadIdx.x < st) red[threadIdx.x] += red[threadIdx.x + st];
    __syncthreads();
  }
  if (threadIdx.x == 0) bsum[blockIdx.x] = red[0];
}

// also zeroes the stats block (piggyback; must run before any finalize kernel)
__global__ void scan_b(const int* __restrict__ bsum, int* __restrict__ boff, int nb,
                       int* __restrict__ rowptr2, int nbins, float* __restrict__ stats) {
  for (int i = threadIdx.x; i < 6 * 128; i += 256) stats[i] = 0.f;
  __shared__ int buf[256];
  __shared__ int carry;
  if (threadIdx.x == 0) carry = 0;
  __syncthreads();
  for (int base = 0; base < nb; base += 256) {
    int i = base + threadIdx.x;
    int v = (i < nb) ? bsum[i] : 0;
    buf[threadIdx.x] = v;
    __syncthreads();
    for (int s = 1; s < 256; s <<= 1) {
      int t = (threadIdx.x >= s) ? buf[threadIdx.x - s] : 0;
      __syncthreads();
      buf[threadIdx.x] += t;
      __syncthreads();
    }
    if (i < nb) boff[i] = carry + buf[threadIdx.x] - v;
    __syncthreads();
    if (threadIdx.x == 255) carry += buf[255];
    __syncthreads();
  }
  if (threadIdx.x == 0) rowptr2[nbins] = carry;
}

// writes rowptr2[i] and seeds cur2[i] with the same value
__global__ void scan_c(const int* __restrict__ in, const int* __restrict__ boff,
                       int* __restrict__ rowptr2, int* __restrict__ cur2, int n) {
  __shared__ int buf[256];
  int base = blockIdx.x * 2048 + threadIdx.x * 8;
  int v[8], p[8];
  int s = 0;
#pragma unroll
  for (int j = 0; j < 8; j++) {
    int i = base + j;
    v[j] = (i < n) ? in[i] : 0;
    p[j] = s;
    s += v[j];
  }
  buf[threadIdx.x] = s;
  __syncthreads();
  for (int st = 1; st < 256; st <<= 1) {
    int t = (threadIdx.x >= st) ? buf[threadIdx.x - st] : 0;
    __syncthreads();
    buf[threadIdx.x] += t;
    __syncthreads();
  }
  int thr_excl = buf[threadIdx.x] - s;
  int b0 = boff[blockIdx.x];
#pragma unroll
  for (int j = 0; j < 8; j++) {
    int i = base + j;
    if (i < n) { int val = b0 + thr_excl + p[j]; rowptr2[i] = val; cur2[i] = val; }
  }
}

// ---------------- one-shot convert: xb + all weight transposes ----------------
__global__ void convert_all(const float* __restrict__ x, const float* __restrict__ W1,
                            const float* __restrict__ W2, const float* __restrict__ Wr1,
                            const float* __restrict__ Wrsc, const float* __restrict__ Wr2,
                            const float* __restrict__ Wsc,
                            unsigned short* __restrict__ xb, unsigned short* __restrict__ W1aug,
                            unsigned short* __restrict__ W2t, unsigned short* __restrict__ rootBt,
                            unsigned short* __restrict__ Wr2t) {
  long i = (long)blockIdx.x * 256 + threadIdx.x;
  const long n0 = 640000, n1 = n0 + 1024000, n2 = n1 + 2048000,
             n3 = n2 + 8192, n4 = n3 + 8192, n5 = n4 + 16384, n6 = n5 + 1024000;
  if (i < n0) {
    xb[i] = f2b(x[i]);
  } else if (i < n1) {
    long j = i - n0; int k = (int)(j >> 7), c = (int)(j & 127);
    W1aug[(long)c * 8000 + k] = f2b(W1[j]);
  } else if (i < n2) {
    long j = i - n1; int k = (int)(j >> 7), c = (int)(j & 127);
    W2t[(long)c * 16000 + k] = f2b(W2[j]);
  } else if (i < n3) {
    long j = i - n2; int k = (int)(j >> 7), c = (int)(j & 127);
    rootBt[c * 64 + k] = f2b(Wr1[j]);
  } else if (i < n4) {
    long j = i - n3; int k = (int)(j >> 7), c = (int)(j & 127);
    rootBt[(128 + c) * 64 + k] = f2b(Wrsc[j]);
  } else if (i < n5) {
    long j = i - n4; int k = (int)(j >> 7), c = (int)(j & 127);
    Wr2t[c * 128 + k] = f2b(Wr2[j]);
  } else if (i < n6) {
    long j = i - n5;
    int c = (int)(j / 8000), kk = (int)(j % 8000);
    W1aug[(long)(128 + c) * 8000 + kk] = f2b(Wsc[(kk & 63) * 128 + c]);
  }
}

// ---------------- scatter: one wave per 8 consecutive bins, register accumulate --
template<int C>
__global__ __launch_bounds__(256) void scatter_bins(
    const unsigned short* __restrict__ Xb, const int* __restrict__ rowptr2,
    const int2* __restrict__ pairs,
    unsigned short* __restrict__ accb, int bin0, int nbins_chunk) {
  int wb0 = (blockIdx.x * 4 + (threadIdx.x >> 6)) * 8;
  if (wb0 >= nbins_chunk) return;
  int lane = threadIdx.x & 63;
  int bin = bin0 + wb0;
  int bounds = 0;
  if (lane < 9) bounds = rowptr2[bin + lane];
  int b[9];
#pragma unroll
  for (int j = 0; j < 9; j++) b[j] = __shfl(bounds, j, 64);
#pragma unroll
  for (int j = 0; j < 8; j++) {
    int wb = wb0 + j;
    if (wb >= nbins_chunk) break;
    float a0 = 0.f, a1 = 0.f;
    for (int p = b[j]; p < b[j + 1]; p++) {
      int2 rec = pairs[p];
      float w = __int_as_float(rec.y);
      if (C == 64) {
        a0 += w * b2f(Xb[(long)rec.x * 64 + lane]);
      } else {
        unsigned u = *(const unsigned*)(Xb + (long)rec.x * 128 + lane * 2);
        a0 += w * b2f((unsigned short)(u & 0xffffu));
        a1 += w * b2f((unsigned short)(u >> 16));
      }
    }
    if (C == 64) {
      accb[(long)wb * 64 + lane] = f2b(a0);
    } else {
      unsigned pk = (unsigned)f2b(a0) | ((unsigned)f2b(a1) << 16);
      *(unsigned*)(accb + (long)wb * 128 + lane * 2) = pk;
    }
  }
}

// ---------------- LDS-staged MFMA GEMM, 128 output cols ----------------
template<int NCOLS, bool ATOMIC>
__global__ __launch_bounds__(256, 2) void gemm_tile(const unsigned short* __restrict__ A,
                                                    const unsigned short* __restrict__ Bt,
                                                    float* __restrict__ C, int M, int K) {
  __shared__ unsigned short As[128 * 32];
  __shared__ unsigned short Bs[128 * 32];
  int wid = threadIdx.x >> 6, lane = threadIdx.x & 63;
  int row0 = blockIdx.x * 128;
  int nslice = gridDim.y;
  int kslice = CDIV(K / 32, nslice) * 32;
  int kbeg = blockIdx.y * kslice;
  int kend = kbeg + kslice; if (kend > K) kend = K;
  if (kbeg >= K) return;

  int sub = lane & 3;
  int rload = lane >> 2;
  int q = lane >> 4, m16 = lane & 15;

  floatx4 acc[2][8];
#pragma unroll
  for (int t = 0; t < 2; t++)
#pragma unroll
    for (int c = 0; c < 8; c++) acc[t][c] = (floatx4){0.f, 0.f, 0.f, 0.f};

  for (int k0 = kbeg; k0 < kend; k0 += 32) {
    __syncthreads();
#pragma unroll
    for (int j = 0; j < 2; j++) {
      int tr = (wid * 2 + j) * 16 + rload;
      int gr = row0 + tr; if (gr >= M) gr = M - 1;
      ld_g2l16(A + (long)gr * K + k0 + sub * 8, As + (wid * 2 + j) * 512);
      ld_g2l16(Bt + (long)tr * K + k0 + sub * 8, Bs + (wid * 2 + j) * 512);
    }
    __syncthreads();
#pragma unroll
    for (int t = 0; t < 2; t++) {
      int arow = wid * 32 + t * 16 + m16;
      short8 a = *(const short8*)(As + arow * 32 + q * 8);
#pragma unroll
      for (int c = 0; c < 8; c++) {
        short8 b = *(const short8*)(Bs + (c * 16 + m16) * 32 + q * 8);
        acc[t][c] = __builtin_amdgcn_mfma_f32_16x16x32_bf16(a, b, acc[t][c], 0, 0, 0);
      }
    }
  }

#pragma unroll
  for (int t = 0; t < 2; t++) {
#pragma unroll
    for (int c = 0; c < 8; c++) {
#pragma unroll
      for (int r = 0; r < 4; r++) {
        int orow = row0 + wid * 32 + t * 16 + q * 4 + r;
        if (orow < M) {
          float* p = &C[(long)orow * NCOLS + c * 16 + m16];
          if (ATOMIC) atomicAdd(p, acc[t][c][r]);
          else *p = acc[t][c][r];
        }
      }
    }
  }
}

// ---------------- 128x256 tile GEMM (conv1+shortcut in one A pass) ----------------
template<bool ATOMIC>
__global__ __launch_bounds__(256, 2) void gemm_tile_w256(const unsigned short* __restrict__ A,
                                                         const unsigned short* __restrict__ Bt,
                                                         float* __restrict__ C, int M, int K) {
  __shared__ unsigned short As[128 * 32];
  __shared__ unsigned short Bs[256 * 32];
  int wid = threadIdx.x >> 6, lane = threadIdx.x & 63;
  int row0 = blockIdx.x * 128;
  int nslice = gridDim.y;
  int kslice = CDIV(K / 32, nslice) * 32;
  int kbeg = blockIdx.y * kslice;
  int kend = kbeg + kslice; if (kend > K) kend = K;
  if (kbeg >= K) return;

  int sub = lane & 3;
  int rload = lane >> 2;
  int q = lane >> 4, m16 = lane & 15;

  floatx4 acc[2][16];
#pragma unroll
  for (int t = 0; t < 2; t++)
#pragma unroll
    for (int c = 0; c < 16; c++) acc[t][c] = (floatx4){0.f, 0.f, 0.f, 0.f};

  for (int k0 = kbeg; k0 < kend; k0 += 32) {
    __syncthreads();
#pragma unroll
    for (int j = 0; j < 2; j++) {
      int tr = (wid * 2 + j) * 16 + rload;
      int gr = row0 + tr; if (gr >= M) gr = M - 1;
      ld_g2l16(A + (long)gr * K + k0 + sub * 8, As + (wid * 2 + j) * 512);
    }
#pragma unroll
    for (int j = 0; j < 4; j++) {
      int tr = (wid * 4 + j) * 16 + rload;
      ld_g2l16(Bt + (long)tr * K + k0 + sub * 8, Bs + (wid * 4 + j) * 512);
    }
    __syncthreads();
#pragma unroll
    for (int t = 0; t < 2; t++) {
      int arow = wid * 32 + t * 16 + m16;
      short8 a = *(const short8*)(As + arow * 32 + q * 8);
#pragma unroll
      for (int c = 0; c < 16; c++) {
        short8 b = *(const short8*)(Bs + (c * 16 + m16) * 32 + q * 8);
        acc[t][c] = __builtin_amdgcn_mfma_f32_16x16x32_bf16(a, b, acc[t][c], 0, 0, 0);
      }
    }
  }

#pragma unroll
  for (int t = 0; t < 2; t++) {
#pragma unroll
    for (int c = 0; c < 16; c++) {
#pragma unroll
      for (int r = 0; r < 4; r++) {
        int orow = row0 + wid * 32 + t * 16 + q * 4 + r;
        if (orow < M) {
          float* p = &C[(long)orow * 256 + c * 16 + m16];
          if (ATOMIC) atomicAdd(p, acc[t][c][r]);
          else *p = acc[t][c][r];
        }
      }
    }
  }
}

// ---------------- epilogues ----------------
static __device__ __forceinline__ float node_deg(const int* __restrict__ rowptr2, int r) {
  return (float)((rowptr2[(r + 1) * KTOT] - rowptr2[r * KTOT]) >> 3);
}

__global__ void finalize_stats(const float* __restrict__ msgaug, const float* __restrict__ root,
                               const float* __restrict__ bias,
                               const int* __restrict__ rowptr2,
                               float* __restrict__ out, float* __restrict__ stats, int n) {
  int c = threadIdx.x & 127;
  float bv = bias[c];
  float s = 0.f, s2 = 0.f;
  long tot = (long)n * COUT;
  long stride = (long)gridDim.x * 256;
  for (long i = (long)blockIdx.x * 256 + threadIdx.x; i < tot; i += stride) {
    int r = (int)(i >> 7);
    float v = msgaug[(long)r * 256 + c] / fmaxf(node_deg(rowptr2, r), 1.0f)
            + root[(long)r * 256 + c] + bv;
    out[i] = v;
    s += v; s2 += v * v;
  }
  __shared__ float ls[256], ls2[256];
  ls[threadIdx.x] = s; ls2[threadIdx.x] = s2;
  __syncthreads();
  if (threadIdx.x < 128) {
    atomicAdd(&stats[c], ls[threadIdx.x] + ls[threadIdx.x + 128]);
    atomicAdd(&stats[128 + c], ls2[threadIdx.x] + ls2[threadIdx.x + 128]);
  }
}

__global__ void finalize2_dual(const float* __restrict__ msg2, const float* __restrict__ rootb2,
                               const float* __restrict__ b2, const float* __restrict__ msgaug,
                               const float* __restrict__ rootb, const float* __restrict__ bsc,
                               const int* __restrict__ rowptr2, float* __restrict__ h2r,
                               float* __restrict__ sraw, float* __restrict__ stats2,
                               float* __restrict__ statssc, int n) {
  int c = threadIdx.x & 127;
  float bv2 = b2[c], bvsc = bsc[c];
  float sa = 0.f, sb = 0.f, ta = 0.f, tb = 0.f;
  long tot = (long)n * COUT;
  long stride = (long)gridDim.x * 256;
  for (long i = (long)blockIdx.x * 256 + threadIdx.x; i < tot; i += stride) {
    int r = (int)(i >> 7);
    float invdeg = 1.0f / fmaxf(node_deg(rowptr2, r), 1.0f);
    float v2 = msg2[i] * invdeg + rootb2[i] + bv2;
    h2r[i] = v2;
    sa += v2; sb += v2 * v2;
    float vs = msgaug[(long)r * 256 + 128 + c] * invdeg
             + rootb[(long)r * 256 + 128 + c] + bvsc;
    sraw[i] = vs;
    ta += vs; tb += vs * vs;
  }
  __shared__ float l0[256], l1[256], l2[256], l3[256];
  l0[threadIdx.x] = sa; l1[threadIdx.x] = sb; l2[threadIdx.x] = ta; l3[threadIdx.x] = tb;
  __syncthreads();
  if (threadIdx.x < 128) {
    atomicAdd(&stats2[c], l0[threadIdx.x] + l0[threadIdx.x + 128]);
    atomicAdd(&stats2[128 + c], l1[threadIdx.x] + l1[threadIdx.x + 128]);
    atomicAdd(&statssc[c], l2[threadIdx.x] + l2[threadIdx.x + 128]);
    atomicAdd(&statssc[128 + c], l3[threadIdx.x] + l3[threadIdx.x + 128]);
  }
}

__global__ void bn_elu_kernel(float* __restrict__ h, unsigned short* __restrict__ hb,
                              const float* __restrict__ stats, const float* __restrict__ g,
                              const float* __restrict__ be, int n) {
  long i = (long)blockIdx.x * 256 + threadIdx.x;
  if (i >= (long)n * COUT) return;
  int c = (int)(i & 127);
  float inv_n = 1.0f / n;
  float mu = stats[c] * inv_n;
  float var = stats[128 + c] * inv_n - mu * mu;
  float v = (h[i] - mu) * rsqrtf(var + EPS) * g[c] + be[c];
  v = v > 0.f ? v : expm1f(v);
  h[i] = v;
  hb[i] = f2b(v);
}

__global__ void final_out_kernel(const float* __restrict__ h2, const float* __restrict__ sraw,
                                 const float* __restrict__ st2, const float* __restrict__ stsc,
                                 const float* __restrict__ g2, const float* __restrict__ be2,
                                 const float* __restrict__ gsc, const float* __restrict__ besc,
                                 float* __restrict__ out, int n) {
  long i = (long)blockIdx.x * 256 + threadIdx.x;
  if (i >= (long)n * COUT) return;
  int c = (int)(i & 127);
  float inv_n = 1.0f / n;
  float mu2 = st2[c] * inv_n;
  float var2 = st2[128 + c] * inv_n - mu2 * mu2;
  float a = (h2[i] - mu2) * rsqrtf(var2 + EPS) * g2[c] + be2[c];
  float musc = stsc[c] * inv_n;
  float varsc = stsc[128 + c] * inv_n - musc * musc;
  float b = (sraw[i] - musc) * rsqrtf(varsc + EPS) * gsc[c] + besc[c];
  float v = a + b;
  out[i] = v > 0.f ? v : expm1f(v);
}

// ---------------- host ----------------
extern "C" void kernel_launch(void* const* d_in, const int* in_sizes, int n_in,
                              void* d_out, int out_size, void* d_ws, size_t ws_size,
                              hipStream_t stream) {
  const float* x    = (const float*)d_in[0];
  const int*   eidx = (const int*)d_in[1];
  const float* attr = (const float*)d_in[2];
  const float* W1   = (const float*)d_in[3];
  const float* Wr1  = (const float*)d_in[4];
  const float* b1   = (const float*)d_in[5];
  const float* g1   = (const float*)d_in[6];
  const float* be1  = (const float*)d_in[7];
  const float* W2   = (const float*)d_in[8];
  const float* Wr2  = (const float*)d_in[9];
  const float* b2   = (const float*)d_in[10];
  const float* g2   = (const float*)d_in[11];
  const float* be2  = (const float*)d_in[12];
  const float* Wsc  = (const float*)d_in[13];
  const float* Wrsc = (const float*)d_in[14];
  const float* bsc  = (const float*)d_in[15];
  const float* gsc  = (const float*)d_in[16];
  const float* besc = (const float*)d_in[17];
  float* out = (float*)d_out;

  const int* src = eidx;
  const int* dst = eidx + N_EDGES;

  char* base = (char*)d_ws;
  size_t off = 0;
  auto alloc = [&](size_t bytes) -> char* {
    char* p = base + off;
    off += (bytes + 255) & ~(size_t)255;
    return p;
  };
  int* cnt2   = (int*)alloc((size_t)NBINS * 4);
  int* ecnt   = (int*)alloc((size_t)N_NODES * 4);      // adjacent to cnt2: one memset
  int* cur2   = (int*)alloc((size_t)NBINS * 4);
  int* rowptr2= (int*)alloc((size_t)(NBINS + 1) * 4);
  const int NB_SCAN = CDIV(NBINS, 2048);
  int* bsum   = (int*)alloc((size_t)(NB_SCAN + 1) * 4);
  int* boff   = (int*)alloc((size_t)(NB_SCAN + 1) * 4);
  int* erowptr= (int*)alloc((size_t)(N_NODES + 1) * 4);
  int* ecur   = (int*)alloc((size_t)N_NODES * 4);
  int* eorder = (int*)alloc((size_t)N_EDGES * 4);
  int2* pairs = (int2*)alloc((size_t)NPAIRS * 8);
  unsigned short* xb    = (unsigned short*)alloc((size_t)N_NODES * CIN * 2);
  unsigned short* hb    = (unsigned short*)alloc((size_t)N_NODES * COUT * 2);
  unsigned short* W1aug = (unsigned short*)alloc((size_t)256 * KTOT * CIN * 2);
  unsigned short* W2t   = (unsigned short*)alloc((size_t)COUT * KTOT * COUT * 2);
  unsigned short* rootBt= (unsigned short*)alloc((size_t)256 * CIN * 2);
  unsigned short* Wr2t  = (unsigned short*)alloc((size_t)COUT * COUT * 2);
  float* msgaug= (float*)alloc((size_t)N_NODES * 256 * 4);    // conv1+shortcut (zeroed)
  float* msg2  = (float*)alloc((size_t)N_NODES * COUT * 4);   // conv2 (zeroed, adjacent)
  float* rootb = (float*)alloc((size_t)N_NODES * 256 * 4);    // [Wr1 | Wrsc] outputs
  float* rootb2= (float*)alloc((size_t)N_NODES * COUT * 4);
  float* h1    = (float*)alloc((size_t)N_NODES * COUT * 4);
  float* h2r   = (float*)alloc((size_t)N_NODES * COUT * 4);
  float* sraw  = (float*)alloc((size_t)N_NODES * COUT * 4);
  float* stats = (float*)alloc(6 * 128 * 4);
  unsigned short* accb = (unsigned short*)(base + off);
  size_t avail = (ws_size > off) ? (ws_size - off) : 0;
  size_t per_node = (size_t)KTOT * COUT * 2;
  size_t chmax = avail / per_node;
  int CH = (int)((chmax < (size_t)N_NODES) ? chmax : (size_t)N_NODES);
  if (CH < 1) CH = 1;
  const int SPLIT = 10;

  // one memset covers cnt2 + ecnt (adjacent allocations)
  hipMemsetAsync(cnt2, 0, (size_t)((char*)ecnt - (char*)cnt2) + (size_t)N_NODES * 4, stream);
  hipMemsetAsync(msgaug, 0, (size_t)N_NODES * (256 + 128) * 4, stream); // msgaug + msg2

  // edge CSR: dst-sorted edge permutation (write locality for the pair sort)
  ecount<<<CDIV(N_EDGES, 256), 256, 0, stream>>>(dst, ecnt, N_EDGES);
  escan<<<1, 256, 0, stream>>>(ecnt, erowptr, ecur, N_NODES);
  efill<<<CDIV(N_EDGES, 256), 256, 0, stream>>>(dst, ecur, eorder, N_EDGES);

  // (dst,k)-pair counting sort in dst-sorted order
  pair_count<<<CDIV(N_EDGES, 256), 256, 0, stream>>>(eorder, dst, attr, cnt2, N_EDGES);
  scan_a<<<NB_SCAN, 256, 0, stream>>>(cnt2, bsum, NBINS);
  scan_b<<<1, 256, 0, stream>>>(bsum, boff, NB_SCAN, rowptr2, NBINS, stats);
  scan_c<<<NB_SCAN, 256, 0, stream>>>(cnt2, boff, rowptr2, cur2, NBINS);
  pair_fill<<<CDIV(N_EDGES, 256), 256, 0, stream>>>(eorder, src, dst, attr, cur2,
                                                    pairs, N_EDGES);

  const long CONV_TOT = 640000L + 1024000L + 2048000L + 8192 + 8192 + 16384 + 1024000L;
  convert_all<<<CDIV(CONV_TOT, 256), 256, 0, stream>>>(x, W1, W2, Wr1, Wrsc, Wr2, Wsc,
                                                       xb, W1aug, W2t, rootBt, Wr2t);

  // ---- conv1 (+ shortcut spline via augmented cols 128..255, single A pass) ----
  for (int c0 = 0; c0 < N_NODES; c0 += CH) {
    int cm = (N_NODES - c0 < CH) ? (N_NODES - c0) : CH;
    int nbc = cm * KTOT;
    scatter_bins<64><<<CDIV(nbc, 32), 256, 0, stream>>>(xb, rowptr2, pairs, accb,
                                                        c0 * KTOT, nbc);
    dim3 g(CDIV(cm, 128), SPLIT);
    gemm_tile_w256<true><<<g, 256, 0, stream>>>(accb, W1aug, msgaug + (size_t)c0 * 256,
                                                cm, KTOT * CIN);
  }
  gemm_tile_w256<false><<<dim3(CDIV(N_NODES, 128), 1), 256, 0, stream>>>(
      xb, rootBt, rootb, N_NODES, CIN);
  finalize_stats<<<64, 256, 0, stream>>>(msgaug, rootb, b1, rowptr2, h1, stats, N_NODES);
  bn_elu_kernel<<<CDIV(N_NODES * COUT, 256), 256, 0, stream>>>(h1, hb, stats, g1, be1, N_NODES);

  // ---- conv2 ----
  for (int c0 = 0; c0 < N_NODES; c0 += CH) {
    int cm = (N_NODES - c0 < CH) ? (N_NODES - c0) : CH;
    int nbc = cm * KTOT;
    scatter_bins<128><<<CDIV(nbc, 32), 256, 0, stream>>>(hb, rowptr2, pairs, accb,
                                                         c0 * KTOT, nbc);
    dim3 g(CDIV(cm, 128), SPLIT);
    gemm_tile<COUT, true><<<g, 256, 0, stream>>>(accb, W2t, msg2 + (size_t)c0 * COUT,
                                                 cm, KTOT * COUT);
  }
  gemm_tile<COUT, false><<<dim3(CDIV(N_NODES, 128), 1), 256, 0, stream>>>(
      hb, Wr2t, rootb2, N_NODES, COUT);
  finalize2_dual<<<64, 256, 0, stream>>>(msg2, rootb2, b2, msgaug, rootb, bsc, rowptr2,
                                         h2r, sraw, stats + 256, stats + 512, N_NODES);

  // ---- output ----
  final_out_kernel<<<CDIV(N_NODES * COUT, 256), 256, 0, stream>>>(
      h2r, sraw, stats + 256, stats + 512, g2, be2, gsc, besc, out, N_NODES);
}